// Round 3
// baseline (86.480 us; speedup 1.0000x reference)
//
#include <hip/hip_runtime.h>

#define HH 512
#define WW 512
#define NB 8
#define NC 128
#define TSX 128               // tile width
#define TSY 64                // tile height
#define NTILES 32             // (512/128) x (512/64) = 4 x 8 per sample
#define NBLK (NB * NTILES)    // 256 blocks x 1024 thr = 4096 waves, 1 blk/CU
#define CUT 30.0f             // exp(-30) ~ 9e-14 << 2e-2 tolerance

// R7 = R6 retry (R6 failed to compile: __builtin_nontemporal_* rejects
// HIP_vector_type pointers; use clang ext_vector_type instead).
// Design: 256 blocks x 1024 thr, tile 128x64, same 4096-wave TLP
// (16 waves/CU, 1 block/CU). Scattered sm gathers 65K->33K, barrier
// chains 512->256. hm/mask loads + gts stores non-temporal (zero reuse;
// keeps sm lines L2-resident for the gather phase). sm loads cached.

typedef float vf4 __attribute__((ext_vector_type(4)));
typedef float vf2 __attribute__((ext_vector_type(2)));

__global__ __launch_bounds__(1024) void ahl_main_kernel(
    const float* __restrict__ pred_hm,
    const float* __restrict__ pred_sm,
    const float* __restrict__ mask,
    const float* __restrict__ ground_res,
    const int*   __restrict__ centers,
    float* __restrict__ out,            // out[0]=sl, out[1]=hl, gts at out+2
    float2* __restrict__ partials) {
    __shared__ float4 sp[NC];
    __shared__ float4 sc[NC];
    __shared__ int s_cnt;
    __shared__ float redS[16];
    __shared__ float redH[16];

    const int b    = blockIdx.x >> 5;          // / NTILES
    const int tile = blockIdx.x & 31;
    const int tx0  = (tile & 3) * TSX;
    const int ty0  = (tile >> 2) * TSY;
    const int tid  = threadIdx.x;

    // thread -> 2 rows x 4 consecutive cols (rows ya and ya+32)
    const int cg  = tid & 31;                  // col group (x4 px), 32 groups
    const int r0  = tid >> 5;                  // 0..31
    const int x0  = tx0 + cg * 4;
    const int ya  = ty0 + r0;
    const int yb  = ya + 32;

    // ---- prefetch epilogue data NOW; latency overlaps phases 0-2
    const size_t sbase = (size_t)b * (HH * WW);
    const size_t ia    = sbase + (size_t)ya * WW + x0;
    const size_t ib    = sbase + (size_t)yb * WW + x0;
    vf4 hmA = __builtin_nontemporal_load((const vf4*)&pred_hm[ia]);
    vf4 smA = *(const vf4*)&pred_sm[ia];
    vf4 mkA = __builtin_nontemporal_load((const vf4*)&mask[ia]);
    vf4 hmB = __builtin_nontemporal_load((const vf4*)&pred_hm[ib]);
    vf4 smB = *(const vf4*)&pred_sm[ib];
    vf4 mkB = __builtin_nontemporal_load((const vf4*)&mask[ib]);

    // ---- phase 0: per-center params (gathers L2-hot across blocks)
    if (tid == 0) s_cnt = 0;
    if (tid < NC) {
        int cy = centers[(b * NC + tid) * 2 + 0];
        int cx = centers[(b * NC + tid) * 2 + 1];
        cy = min(max(cy, 0), HH - 1);
        cx = min(max(cx, 0), WW - 1);
        float smv = pred_sm[sbase + (size_t)cy * WW + cx];
        float g   = ground_res[b];
        float size = (0.2f / g) * (1.0f + fmaxf(smv, 0.0f));
        float s = 0.70710678f / size;          // sqrt(1/(2 size^2))
        sp[tid] = make_float4(s, -(float)cx * s, -(float)cy * s, 0.0f);
    }
    __syncthreads();

    // ---- phase 1: cull centers vs 128x64 tile rect (scaled distance)
    if (tid < NC) {
        float4 P = sp[tid];
        float a0 = fmaf((float)tx0,             P.x, P.y);
        float a1 = fmaf((float)(tx0 + TSX - 1), P.x, P.y);
        float b0 = fmaf((float)ty0,             P.x, P.z);
        float b1 = fmaf((float)(ty0 + TSY - 1), P.x, P.z);
        float dx = fmaxf(0.0f, fmaxf(a0, -a1));
        float dy = fmaxf(0.0f, fmaxf(b0, -b1));
        if (fmaf(dx, dx, dy * dy) < CUT) {
            int i = atomicAdd(&s_cnt, 1);
            sc[i] = P;
        }
    }
    __syncthreads();
    const int cnt = s_cnt;

    // ---- phase 2: min-splat; column term d^2 shared across both rows
    const float yfa = (float)ya;
    const float yfb = (float)yb;
    float xf[4];
#pragma unroll
    for (int j = 0; j < 4; j++) xf[j] = (float)(x0 + j);
    float mA[4] = {1e30f, 1e30f, 1e30f, 1e30f};
    float mB[4] = {1e30f, 1e30f, 1e30f, 1e30f};

    for (int i = 0; i < cnt; i++) {
        float4 P = sc[i];
        float da = fmaf(yfa, P.x, P.z); da *= da;
        float db = fmaf(yfb, P.x, P.z); db *= db;
#pragma unroll
        for (int j = 0; j < 4; j++) {
            float d  = fmaf(xf[j], P.x, P.y);
            float dd = d * d;
            mA[j] = fminf(mA[j], dd + da);
            mB[j] = fminf(mB[j], dd + db);
        }
    }

    // ---- phase 3: epilogue (data already in registers)
    float gA0 = __expf(-mA[0]), gA1 = __expf(-mA[1]);
    float gA2 = __expf(-mA[2]), gA3 = __expf(-mA[3]);
    float gB0 = __expf(-mB[0]), gB1 = __expf(-mB[1]);
    float gB2 = __expf(-mB[2]), gB3 = __expf(-mB[3]);

    vf2* gpA = (vf2*)&out[2 + ia];             // 8B-aligned (ia % 4 == 0)
    vf2 sA0; sA0.x = gA0; sA0.y = gA1;
    vf2 sA1; sA1.x = gA2; sA1.y = gA3;
    __builtin_nontemporal_store(sA0, gpA);
    __builtin_nontemporal_store(sA1, gpA + 1);
    vf2* gpB = (vf2*)&out[2 + ib];
    vf2 sB0; sB0.x = gB0; sB0.y = gB1;
    vf2 sB1; sB1.x = gB2; sB1.y = gB3;
    __builtin_nontemporal_store(sB0, gpB);
    __builtin_nontemporal_store(sB1, gpB + 1);

    float d0 = hmA.x - gA0, d1 = hmA.y - gA1, d2 = hmA.z - gA2, d3 = hmA.w - gA3;
    float lhm = d0 * d0 * mkA.x;
    lhm = fmaf(d1 * d1, mkA.y, lhm);
    lhm = fmaf(d2 * d2, mkA.z, lhm);
    lhm = fmaf(d3 * d3, mkA.w, lhm);
    d0 = hmB.x - gB0; d1 = hmB.y - gB1; d2 = hmB.z - gB2; d3 = hmB.w - gB3;
    lhm = fmaf(d0 * d0, mkB.x, lhm);
    lhm = fmaf(d1 * d1, mkB.y, lhm);
    lhm = fmaf(d2 * d2, mkB.z, lhm);
    lhm = fmaf(d3 * d3, mkB.w, lhm);

    float lsc = smA.x * smA.x;
    lsc = fmaf(smA.y, smA.y, lsc);
    lsc = fmaf(smA.z, smA.z, lsc);
    lsc = fmaf(smA.w, smA.w, lsc);
    lsc = fmaf(smB.x, smB.x, lsc);
    lsc = fmaf(smB.y, smB.y, lsc);
    lsc = fmaf(smB.z, smB.z, lsc);
    lsc = fmaf(smB.w, smB.w, lsc);

    // block reduction (16 waves)
#pragma unroll
    for (int off = 32; off > 0; off >>= 1) {
        lhm += __shfl_down(lhm, off);
        lsc += __shfl_down(lsc, off);
    }
    int lane = tid & 63, wid = tid >> 6;
    if (lane == 0) { redS[wid] = lsc; redH[wid] = lhm; }
    __syncthreads();
    if (tid == 0) {
        float ts = 0.0f, th = 0.0f;
#pragma unroll
        for (int w = 0; w < 16; w++) { ts += redS[w]; th += redH[w]; }
        partials[blockIdx.x] = make_float2(ts, th);   // plain store; kernel
    }                                                  // boundary orders it
}

__global__ __launch_bounds__(256) void ahl_reduce_kernel(
    const float2* __restrict__ partials, float* __restrict__ out) {
    __shared__ float red[8];
    const int tid = threadIdx.x;
    float ts = 0.0f, th = 0.0f;
    if (tid < NBLK) {                          // 1 slot per thread
        float2 a = partials[tid];
        ts = a.x;
        th = a.y;
    }
#pragma unroll
    for (int off = 32; off > 0; off >>= 1) {
        ts += __shfl_down(ts, off);
        th += __shfl_down(th, off);
    }
    int lane = tid & 63, wid = tid >> 6;
    if (lane == 0) { red[wid] = ts; red[4 + wid] = th; }
    __syncthreads();
    if (tid == 0) {
        const float invc = 1.0f / (float)((size_t)NB * HH * WW);
        out[0] = (red[0] + red[1] + red[2] + red[3]) * invc;
        out[1] = (red[4] + red[5] + red[6] + red[7]) * invc;
    }
}

extern "C" void kernel_launch(void* const* d_in, const int* in_sizes, int n_in,
                              void* d_out, int out_size, void* d_ws, size_t ws_size,
                              hipStream_t stream) {
    const float* pred_hm    = (const float*)d_in[0];
    const float* pred_sm    = (const float*)d_in[1];
    const float* ground_res = (const float*)d_in[2];
    const float* mask       = (const float*)d_in[3];
    const int*   centers    = (const int*)d_in[4];
    float* out = (float*)d_out;
    float2* partials = (float2*)d_ws;   // NBLK float2 = 2 KB

    ahl_main_kernel<<<NBLK, 1024, 0, stream>>>(pred_hm, pred_sm, mask,
                                               ground_res, centers, out,
                                               partials);
    ahl_reduce_kernel<<<1, 256, 0, stream>>>(partials, out);
}

// Round 4
// 82.669 us; speedup vs baseline: 1.0461x; 1.0461x over previous
//
#include <hip/hip_runtime.h>

#define HH 512
#define WW 512
#define NB 8
#define NC 128
#define TS 64                 // 64x64 tile
#define NTILES 64             // 8x8 tiles per sample
#define NBLK (NB * NTILES)    // 512 blocks x 512 thr = 4096 waves, 2 blk/CU
#define CUT 30.0f             // exp(-30) ~ 9e-14 << 2e-2 tolerance

// R8: revert R3 regression (256x1024 + nt = 86.5us; 1 blk/CU lost prologue
// overlap). Back to R1's measured-best 512x512 (83.9us), with ONE change:
// single-wave ballot-compacted prologue. R1's sp[] + first barrier were dead
// (phase 1 read only sp[tid] = own value). Now wave 0 computes+culls all 128
// centers (2/lane), compacts via __ballot/popc prefix into sc[] -- no shared
// atomic, no init barrier. 2 barriers -> 1, other 7 waves wait once.

__global__ __launch_bounds__(512) void ahl_main_kernel(
    const float* __restrict__ pred_hm,
    const float* __restrict__ pred_sm,
    const float* __restrict__ mask,
    const float* __restrict__ ground_res,
    const int*   __restrict__ centers,
    float* __restrict__ out,            // out[0]=sl, out[1]=hl, gts at out+2
    float2* __restrict__ partials) {
    __shared__ float4 sc[NC];
    __shared__ int s_cnt;
    __shared__ float redS[8];
    __shared__ float redH[8];

    const int b    = blockIdx.x >> 6;          // / NTILES
    const int tile = blockIdx.x & 63;
    const int tx0  = (tile & 7) * TS;
    const int ty0  = (tile >> 3) * TS;
    const int tid  = threadIdx.x;

    // thread -> 2 rows x 4 consecutive cols (rows ya and ya+32)
    const int cg  = tid & 15;                  // col group (x4 px)
    const int r0  = tid >> 4;                  // 0..31
    const int x0  = tx0 + cg * 4;
    const int ya  = ty0 + r0;
    const int yb  = ya + 32;

    // ---- prefetch epilogue data NOW; latency overlaps prologue + splat
    const size_t sbase = (size_t)b * (HH * WW);
    const size_t ia    = sbase + (size_t)ya * WW + x0;
    const size_t ib    = sbase + (size_t)yb * WW + x0;
    float4 hmA = *(const float4*)&pred_hm[ia];
    float4 smA = *(const float4*)&pred_sm[ia];
    float4 mkA = *(const float4*)&mask[ia];
    float4 hmB = *(const float4*)&pred_hm[ib];
    float4 smB = *(const float4*)&pred_sm[ib];
    float4 mkB = *(const float4*)&mask[ib];

    // ---- fused prologue: wave 0 computes, culls, ballot-compacts 128 centers
    if (tid < 64) {
        const int lane = tid;
        const unsigned long long below = (1ull << lane) - 1ull;
        const float g    = ground_res[b];
        const float base = 0.2f / g;

        // center pair: lane and lane+64
        int2 c0 = *(const int2*)&centers[(b * NC + lane) * 2];
        int2 c1 = *(const int2*)&centers[(b * NC + lane + 64) * 2];

        float4 P0, P1;
        bool k0, k1;
        {
            int cy = min(max(c0.x, 0), HH - 1);
            int cx = min(max(c0.y, 0), WW - 1);
            float smv  = pred_sm[sbase + (size_t)cy * WW + cx];
            float size = base * (1.0f + fmaxf(smv, 0.0f));
            float s    = 0.70710678f / size;   // sqrt(1/(2 size^2))
            P0 = make_float4(s, -(float)cx * s, -(float)cy * s, 0.0f);
            float a0 = fmaf((float)tx0,            P0.x, P0.y);
            float a1 = fmaf((float)(tx0 + TS - 1), P0.x, P0.y);
            float b0 = fmaf((float)ty0,            P0.x, P0.z);
            float b1 = fmaf((float)(ty0 + TS - 1), P0.x, P0.z);
            float dx = fmaxf(0.0f, fmaxf(a0, -a1));
            float dy = fmaxf(0.0f, fmaxf(b0, -b1));
            k0 = fmaf(dx, dx, dy * dy) < CUT;
        }
        {
            int cy = min(max(c1.x, 0), HH - 1);
            int cx = min(max(c1.y, 0), WW - 1);
            float smv  = pred_sm[sbase + (size_t)cy * WW + cx];
            float size = base * (1.0f + fmaxf(smv, 0.0f));
            float s    = 0.70710678f / size;
            P1 = make_float4(s, -(float)cx * s, -(float)cy * s, 0.0f);
            float a0 = fmaf((float)tx0,            P1.x, P1.y);
            float a1 = fmaf((float)(tx0 + TS - 1), P1.x, P1.y);
            float b0 = fmaf((float)ty0,            P1.x, P1.z);
            float b1 = fmaf((float)(ty0 + TS - 1), P1.x, P1.z);
            float dx = fmaxf(0.0f, fmaxf(a0, -a1));
            float dy = fmaxf(0.0f, fmaxf(b0, -b1));
            k1 = fmaf(dx, dx, dy * dy) < CUT;
        }

        unsigned long long m0 = __ballot(k0);
        if (k0) sc[__popcll(m0 & below)] = P0;
        int base1 = __popcll(m0);
        unsigned long long m1 = __ballot(k1);
        if (k1) sc[base1 + __popcll(m1 & below)] = P1;
        if (lane == 0) s_cnt = base1 + __popcll(m1);
    }
    __syncthreads();
    const int cnt = s_cnt;

    // ---- splat: min over culled centers; column term shared across rows
    const float yfa = (float)ya;
    const float yfb = (float)yb;
    float xf[4];
#pragma unroll
    for (int j = 0; j < 4; j++) xf[j] = (float)(x0 + j);
    float mA[4] = {1e30f, 1e30f, 1e30f, 1e30f};
    float mB[4] = {1e30f, 1e30f, 1e30f, 1e30f};

    for (int i = 0; i < cnt; i++) {
        float4 P = sc[i];
        float da = fmaf(yfa, P.x, P.z); da *= da;
        float db = fmaf(yfb, P.x, P.z); db *= db;
#pragma unroll
        for (int j = 0; j < 4; j++) {
            float d  = fmaf(xf[j], P.x, P.y);
            float dd = d * d;
            mA[j] = fminf(mA[j], dd + da);
            mB[j] = fminf(mB[j], dd + db);
        }
    }

    // ---- epilogue (data already in registers)
    float gA0 = __expf(-mA[0]), gA1 = __expf(-mA[1]);
    float gA2 = __expf(-mA[2]), gA3 = __expf(-mA[3]);
    float gB0 = __expf(-mB[0]), gB1 = __expf(-mB[1]);
    float gB2 = __expf(-mB[2]), gB3 = __expf(-mB[3]);

    float2* gpA = (float2*)&out[2 + ia];       // 8B-aligned (ia % 4 == 0)
    gpA[0] = make_float2(gA0, gA1);
    gpA[1] = make_float2(gA2, gA3);
    float2* gpB = (float2*)&out[2 + ib];
    gpB[0] = make_float2(gB0, gB1);
    gpB[1] = make_float2(gB2, gB3);

    float d0 = hmA.x - gA0, d1 = hmA.y - gA1, d2 = hmA.z - gA2, d3 = hmA.w - gA3;
    float lhm = d0 * d0 * mkA.x;
    lhm = fmaf(d1 * d1, mkA.y, lhm);
    lhm = fmaf(d2 * d2, mkA.z, lhm);
    lhm = fmaf(d3 * d3, mkA.w, lhm);
    d0 = hmB.x - gB0; d1 = hmB.y - gB1; d2 = hmB.z - gB2; d3 = hmB.w - gB3;
    lhm = fmaf(d0 * d0, mkB.x, lhm);
    lhm = fmaf(d1 * d1, mkB.y, lhm);
    lhm = fmaf(d2 * d2, mkB.z, lhm);
    lhm = fmaf(d3 * d3, mkB.w, lhm);

    float lsc = smA.x * smA.x;
    lsc = fmaf(smA.y, smA.y, lsc);
    lsc = fmaf(smA.z, smA.z, lsc);
    lsc = fmaf(smA.w, smA.w, lsc);
    lsc = fmaf(smB.x, smB.x, lsc);
    lsc = fmaf(smB.y, smB.y, lsc);
    lsc = fmaf(smB.z, smB.z, lsc);
    lsc = fmaf(smB.w, smB.w, lsc);

    // block reduction (8 waves)
#pragma unroll
    for (int off = 32; off > 0; off >>= 1) {
        lhm += __shfl_down(lhm, off);
        lsc += __shfl_down(lsc, off);
    }
    int lane = tid & 63, wid = tid >> 6;
    if (lane == 0) { redS[wid] = lsc; redH[wid] = lhm; }
    __syncthreads();
    if (tid == 0) {
        float ts = 0.0f, th = 0.0f;
#pragma unroll
        for (int w = 0; w < 8; w++) { ts += redS[w]; th += redH[w]; }
        partials[blockIdx.x] = make_float2(ts, th);   // plain store; kernel
    }                                                  // boundary orders it
}

__global__ __launch_bounds__(256) void ahl_reduce_kernel(
    const float2* __restrict__ partials, float* __restrict__ out) {
    __shared__ float red[8];
    const int tid = threadIdx.x;
    float ts = 0.0f, th = 0.0f;
    for (int s = tid; s < NBLK; s += 256) {    // 2 slots per thread
        float2 a = partials[s];
        ts += a.x;
        th += a.y;
    }
#pragma unroll
    for (int off = 32; off > 0; off >>= 1) {
        ts += __shfl_down(ts, off);
        th += __shfl_down(th, off);
    }
    int lane = tid & 63, wid = tid >> 6;
    if (lane == 0) { red[wid] = ts; red[4 + wid] = th; }
    __syncthreads();
    if (tid == 0) {
        const float invc = 1.0f / (float)((size_t)NB * HH * WW);
        out[0] = (red[0] + red[1] + red[2] + red[3]) * invc;
        out[1] = (red[4] + red[5] + red[6] + red[7]) * invc;
    }
}

extern "C" void kernel_launch(void* const* d_in, const int* in_sizes, int n_in,
                              void* d_out, int out_size, void* d_ws, size_t ws_size,
                              hipStream_t stream) {
    const float* pred_hm    = (const float*)d_in[0];
    const float* pred_sm    = (const float*)d_in[1];
    const float* ground_res = (const float*)d_in[2];
    const float* mask       = (const float*)d_in[3];
    const int*   centers    = (const int*)d_in[4];
    float* out = (float*)d_out;
    float2* partials = (float2*)d_ws;   // NBLK float2 = 4 KB

    ahl_main_kernel<<<NBLK, 512, 0, stream>>>(pred_hm, pred_sm, mask,
                                              ground_res, centers, out,
                                              partials);
    ahl_reduce_kernel<<<1, 256, 0, stream>>>(partials, out);
}